// Round 9
// baseline (240.057 us; speedup 1.0000x reference)
//
#include <hip/hip_runtime.h>
#include <hip/hip_bf16.h>

// FullAttention: N=2, L=S=2048, H=16, E=D=64, fp32 in/out, additive mask.
// R9: in-kernel split-combine (atomic last-arriver; no combine kernel, Out
// written once), rs computed by ones-row x16 MFMA (VALU -> MFMA pipe),
// bf16 fragment-order partials. Otherwise R8 structure: QK x32 from LDS,
// PV x16 straight from registers, mask bf16 prefetch, 32KB LDS dbuf.

typedef short bf16x8 __attribute__((ext_vector_type(8)));
typedef short short4v __attribute__((ext_vector_type(4)));
typedef unsigned uint2v __attribute__((ext_vector_type(2)));
typedef unsigned uint4v __attribute__((ext_vector_type(4)));
typedef float f32x4 __attribute__((ext_vector_type(4)));

constexpr int Nb = 2, Lq = 2048, Sk = 2048, Hh = 16, Ee = 64, Dd = 64;
constexpr int BM = 128;     // Q rows per block (4 waves x 32)
constexpr int BN = 64;      // K/V rows per S-tile
constexpr int NT = Sk / BN; // 32 tiles
constexpr int KVB = 4096;   // KV prep blocks
constexpr int MSKB = 2048;  // mask prep blocks
constexpr float SCALE_LOG2E = 0.125f * 1.4426950408889634f;  // (1/sqrt(64)) * log2(e)

__device__ __forceinline__ short f2bf(float f) {
  union { float f; unsigned u; } v; v.f = f;
  unsigned r = (v.u + 0x7fffu + ((v.u >> 16) & 1u)) >> 16;  // RNE
  return (short)r;
}

__device__ __forceinline__ unsigned pack_bf16x2(float a, float b) {
  union { __hip_bfloat162 h; unsigned u; } v;
  float2 f; f.x = a; f.y = b;
  v.h = __float22bfloat162_rn(f);
  return v.u;
}

__device__ __forceinline__ float bf_lo(unsigned u) { return __uint_as_float(u << 16); }
__device__ __forceinline__ float bf_hi(unsigned u) { return __uint_as_float(u & 0xffff0000u); }

__device__ __forceinline__ void async_copy16(const void* g, void* l) {
  __builtin_amdgcn_global_load_lds(
      (const __attribute__((address_space(1))) unsigned int*)g,
      (__attribute__((address_space(3))) unsigned int*)l, 16, 0, 0);
}

// KV tile layout (8192 shorts = 16KB):
//   [0,4096): K chunks (sb,kc): lane l holds K[s=16sb+c][e=32kc+8quad+j] (x32 A-frag)
//   [4096,8192): V chunks (db,sb): lane l holds V^T[d=16db+c][s=16sb+4quad+j] (x16 A-frag)
__global__ __launch_bounds__(256) void prep_all(const float* __restrict__ K,
                                                const float* __restrict__ V,
                                                const float* __restrict__ M,
                                                short* __restrict__ KVf,
                                                short* __restrict__ Mg,
                                                int* __restrict__ Fl) {
  if (blockIdx.x == 0) {   // zero the 512 combine flags
    Fl[threadIdx.x] = 0;
    Fl[threadIdx.x + 256] = 0;
  }
  if (blockIdx.x < KVB) {
    int gid = blockIdx.x * 256 + threadIdx.x;  // 8-short unit index
    int off8 = gid & 1023;                     // unit within 8192-short tile
    int t  = (gid >> 10) & 31;
    int nh = gid >> 15;
    int n = nh >> 4, h = nh & 15;
    short* dst = KVf + ((size_t)(nh * NT + t)) * 8192 + off8 * 8;
    if (off8 < 512) {             // K region
      int ch = off8 >> 6;
      int l  = off8 & 63;
      int sb = ch >> 1, kc = ch & 1, c = l & 15, quad = l >> 4;
      const float* p = K + (((size_t)n * Sk + (t * 64 + sb * 16 + c)) * Hh + h) * Ee
                         + kc * 32 + quad * 8;
      float4 x = *(const float4*)(p);
      float4 y = *(const float4*)(p + 4);
      bf16x8 o;
      o[0] = f2bf(x.x); o[1] = f2bf(x.y); o[2] = f2bf(x.z); o[3] = f2bf(x.w);
      o[4] = f2bf(y.x); o[5] = f2bf(y.y); o[6] = f2bf(y.z); o[7] = f2bf(y.w);
      *(bf16x8*)dst = o;
    } else {                      // V region
      int pos = off8 - 512;
      int vch = pos >> 5;         // chunk 0..15: db=vch>>2, sb=vch&3
      int l0  = (pos & 31) * 2;
      int db = vch >> 2, sb = vch & 3;
      bf16x8 o;
#pragma unroll
      for (int i = 0; i < 2; ++i) {
        int l = l0 + i, c = l & 15, quad = l >> 4;
        const float* p = V + (((size_t)n * Sk + (t * 64 + sb * 16 + quad * 4)) * Hh + h) * Dd
                           + db * 16 + c;
#pragma unroll
        for (int j = 0; j < 4; ++j) o[i * 4 + j] = f2bf(p[(size_t)j * Hh * Dd]);
      }
      *(bf16x8*)dst = o;
    }
  } else {
    // Mask -> bf16*SCALE_LOG2E, lane-contiguous fragment order.
    int u = (blockIdx.x - KVB) * 256 + threadIdx.x;   // 0..524287
    int sub  = u & 3;            // cb*2 + sbp
    int lane = (u >> 2) & 63;
    int t    = (u >> 8) & 31;
    int qw   = u >> 13;          // qt*4 + w
    int cb = sub >> 1, sbp = sub & 1;
    int cc = lane & 15, quad = lane >> 4;
    int row = (qw >> 2) * 128 + (qw & 3) * 32 + cb * 16 + cc;
    short o[8];
#pragma unroll
    for (int k = 0; k < 2; ++k) {
      int sb = sbp * 2 + k;
      float4 mv = *(const float4*)(M + (size_t)row * Sk + t * 64 + sb * 16 + quad * 4);
      o[k * 4 + 0] = f2bf(mv.x * SCALE_LOG2E);
      o[k * 4 + 1] = f2bf(mv.y * SCALE_LOG2E);
      o[k * 4 + 2] = f2bf(mv.z * SCALE_LOG2E);
      o[k * 4 + 3] = f2bf(mv.w * SCALE_LOG2E);
    }
    *(bf16x8*)(Mg + (size_t)u * 8) = *(const bf16x8*)o;
  }
}

__global__ __launch_bounds__(256, 4) void attn_fwd(
    const float* __restrict__ Q, const short* __restrict__ KVf,
    const short* __restrict__ Mg, float* __restrict__ Out,
    short* __restrict__ Pp, float* __restrict__ rsP, int* __restrict__ Fl)
{
  __shared__ short KV[2][8192];   // K+V fragment tile, double-buffered (2x16KB)
  __shared__ int role;

  const int tid  = threadIdx.x;
  const int lane = tid & 63;
  const int w    = tid >> 6;     // wave 0..3
  const int quad = lane >> 4;    // 0..3
  const int c    = lane & 15;    // 0..15

  // XCD-aware decode: XCD (id&7) hosts 4 nh values; sp doesn't change id&7,
  // so split partners share an XCD (L2-local partial exchange).
  const int id   = blockIdx.x;
  const int slot = id >> 3;
  const int nh   = (id & 7) * 4 + (slot & 3);
  const int qt   = (slot >> 2) & 15;
  const int sp   = slot >> 6;
  const int n    = nh >> 4;
  const int h    = nh & 15;

  const int row0 = qt * BM + w * 32;   // wave's first global q row
  const int t0 = sp * (NT / 2), tc = NT / 2;

  // ---- Q fragments, pre-scaled (B-operand x32 layout), 2 q-rows per lane ----
  bf16x8 qfrag[2][2];   // [cb][kc]
#pragma unroll
  for (int cb = 0; cb < 2; ++cb) {
    const float* qp = Q + (((size_t)n * Lq + (row0 + cb * 16 + c)) * Hh + h) * Ee;
#pragma unroll
    for (int kc = 0; kc < 2; ++kc) {
      const float* p = qp + kc * 32 + quad * 8;
      float4 x = *(const float4*)(p);
      float4 y = *(const float4*)(p + 4);
      bf16x8 f;
      f[0] = f2bf(x.x * SCALE_LOG2E); f[1] = f2bf(x.y * SCALE_LOG2E);
      f[2] = f2bf(x.z * SCALE_LOG2E); f[3] = f2bf(x.w * SCALE_LOG2E);
      f[4] = f2bf(y.x * SCALE_LOG2E); f[5] = f2bf(y.y * SCALE_LOG2E);
      f[6] = f2bf(y.z * SCALE_LOG2E); f[7] = f2bf(y.w * SCALE_LOG2E);
      qfrag[cb][kc] = f;
    }
  }

  // Ones A-fragment for rs: A[m][k] = (m==0) -> D[0][q] = sum_k P[k][q]
  short4v ones;
  {
    short one = (c == 0) ? (short)0x3F80 : (short)0;
    ones[0] = one; ones[1] = one; ones[2] = one; ones[3] = one;
  }

  f32x4 o[2][4], o_rs[2];
#pragma unroll
  for (int cb = 0; cb < 2; ++cb) {
    o_rs[cb][0] = 0.f; o_rs[cb][1] = 0.f; o_rs[cb][2] = 0.f; o_rs[cb][3] = 0.f;
#pragma unroll
    for (int db = 0; db < 4; ++db) { o[cb][db][0] = 0.f; o[cb][db][1] = 0.f; o[cb][db][2] = 0.f; o[cb][db][3] = 0.f; }
  }

  const short* kvt = KVf + (size_t)nh * NT * 8192;
  const short* mbase = Mg + (size_t)(qt * 4 + w) * 65536 + lane * 32;

  // ---- prologue: async-stage KV tile t0; load mask frags for t0 ----
#pragma unroll
  for (int i = 0; i < 4; ++i) {
    int seg = w * 4 + i;
    async_copy16(kvt + ((size_t)t0 * 8192) + seg * 512 + lane * 8, &KV[0][seg * 512 + lane * 8]);
  }
  uint4v mcur[4], mnxt[4];
#pragma unroll
  for (int i = 0; i < 4; ++i) mcur[i] = *(const uint4v*)(mbase + (size_t)t0 * 2048 + i * 8);
  __syncthreads();

  for (int tt = 0; tt < tc; ++tt) {
    const int t = t0 + tt;
    const int buf = tt & 1;

    if (tt + 1 < tc) {
      const short* gm = mbase + (size_t)(t + 1) * 2048;
#pragma unroll
      for (int i = 0; i < 4; ++i) mnxt[i] = *(const uint4v*)(gm + i * 8);
      const short* gk = kvt + (size_t)(t + 1) * 8192;
#pragma unroll
      for (int i = 0; i < 4; ++i) {
        int seg = w * 4 + i;
        async_copy16(gk + seg * 512 + lane * 8, &KV[buf ^ 1][seg * 512 + lane * 8]);
      }
    }

    const short* kb = &KV[buf][0];

    // ---- C-init from prefetched mask frags ----
    f32x4 sacc[2][4];
#pragma unroll
    for (int cb = 0; cb < 2; ++cb)
#pragma unroll
      for (int sbp = 0; sbp < 2; ++sbp) {
        uint4v m = mcur[cb * 2 + sbp];
        sacc[cb][sbp * 2 + 0][0] = bf_lo(m.x); sacc[cb][sbp * 2 + 0][1] = bf_hi(m.x);
        sacc[cb][sbp * 2 + 0][2] = bf_lo(m.y); sacc[cb][sbp * 2 + 0][3] = bf_hi(m.y);
        sacc[cb][sbp * 2 + 1][0] = bf_lo(m.z); sacc[cb][sbp * 2 + 1][1] = bf_hi(m.z);
        sacc[cb][sbp * 2 + 1][2] = bf_lo(m.w); sacc[cb][sbp * 2 + 1][3] = bf_hi(m.w);
      }

    // ---- S^T = K Q^T (x32 MFMAs) ----
#pragma unroll
    for (int kc = 0; kc < 2; ++kc) {
#pragma unroll
      for (int sb = 0; sb < 4; ++sb) {
        bf16x8 kfrag = *(const bf16x8*)&kb[(sb * 2 + kc) * 512 + lane * 8];
#pragma unroll
        for (int cb = 0; cb < 2; ++cb)
          sacc[cb][sb] = __builtin_amdgcn_mfma_f32_16x16x32_bf16(kfrag, qfrag[cb][kc], sacc[cb][sb], 0, 0, 0);
      }
    }

    // ---- p = exp2(sacc), pack straight into x16 B-frags (no rs adds) ----
    short4v pv[2][4];
#pragma unroll
    for (int cb = 0; cb < 2; ++cb)
#pragma unroll
      for (int sb = 0; sb < 4; ++sb) {
        float p0 = __builtin_amdgcn_exp2f(sacc[cb][sb][0]);
        float p1 = __builtin_amdgcn_exp2f(sacc[cb][sb][1]);
        float p2 = __builtin_amdgcn_exp2f(sacc[cb][sb][2]);
        float p3 = __builtin_amdgcn_exp2f(sacc[cb][sb][3]);
        union { uint2v u; short4v s; } uu;
        uu.u.x = pack_bf16x2(p0, p1);
        uu.u.y = pack_bf16x2(p2, p3);
        pv[cb][sb] = uu.s;
      }

    // ---- O^T += V^T P^T (x16); rs via ones-row MFMA on the same B-frags ----
#pragma unroll
    for (int sb = 0; sb < 4; ++sb) {
#pragma unroll
      for (int db = 0; db < 4; ++db) {
        short4v vfrag = *(const short4v*)&kb[4096 + (db * 4 + sb) * 256 + lane * 4];
#pragma unroll
        for (int cb = 0; cb < 2; ++cb)
          o[cb][db] = __builtin_amdgcn_mfma_f32_16x16x16bf16_1k(vfrag, pv[cb][sb], o[cb][db], 0, 0, 0);
      }
#pragma unroll
      for (int cb = 0; cb < 2; ++cb)
        o_rs[cb] = __builtin_amdgcn_mfma_f32_16x16x16bf16_1k(ones, pv[cb][sb], o_rs[cb], 0, 0, 0);
    }

    __syncthreads();
#pragma unroll
    for (int i = 0; i < 4; ++i) mcur[i] = mnxt[i];
  }

  // ---- rs: only quad0/r0 nonzero -> quad-sum broadcasts the total ----
  float rsv[2];
#pragma unroll
  for (int cb = 0; cb < 2; ++cb) {
    float v = o_rs[cb][0];
    v += __shfl_xor(v, 16, 64);
    v += __shfl_xor(v, 32, 64);
    rsv[cb] = v;
  }

  // ---- split combine: first arriver writes partial, second combines ----
  const int slice = nh * 16 + qt;
  if (tid == 0) role = atomicAdd(&Fl[slice], 1);
  __syncthreads();

  if (role == 0) {
    // write bf16 partial O in fragment order + fp32 rs, then signal
#pragma unroll
    for (int cb = 0; cb < 2; ++cb) {
      short* pp = Pp + ((size_t)(slice * 4 + w) * 2 + cb) * 1024 + lane * 4;
#pragma unroll
      for (int db = 0; db < 4; ++db) {
        uint2v u;
        u.x = pack_bf16x2(o[cb][db][0], o[cb][db][1]);
        u.y = pack_bf16x2(o[cb][db][2], o[cb][db][3]);
        *(uint2v*)(pp + db * 256) = u;
      }
      if (quad == 0) rsP[slice * 128 + w * 32 + cb * 16 + c] = rsv[cb];
    }
    __threadfence();
    if (tid == 0) atomicAdd(&Fl[slice], 1);
  } else {
    if (tid == 0) {
      while (atomicAdd(&Fl[slice], 0) < 3) __builtin_amdgcn_s_sleep(8);
    }
    __syncthreads();
    __threadfence();
#pragma unroll
    for (int cb = 0; cb < 2; ++cb) {
      const short* pp = Pp + ((size_t)(slice * 4 + w) * 2 + cb) * 1024 + lane * 4;
      float rs_tot = rsv[cb] + rsP[slice * 128 + w * 32 + cb * 16 + c];
      float inv = 1.0f / rs_tot;
      const int qrow = row0 + cb * 16 + c;
      float* op = Out + (((size_t)n * Lq + qrow) * Hh + h) * Dd + quad * 4;
#pragma unroll
      for (int db = 0; db < 4; ++db) {
        uint2v u = *(const uint2v*)(pp + db * 256);
        float4 ov;
        ov.x = (o[cb][db][0] + bf_lo(u.x)) * inv;
        ov.y = (o[cb][db][1] + bf_hi(u.x)) * inv;
        ov.z = (o[cb][db][2] + bf_lo(u.y)) * inv;
        ov.w = (o[cb][db][3] + bf_hi(u.y)) * inv;
        *(float4*)(op + db * 16) = ov;
      }
    }
  }
}

extern "C" void kernel_launch(void* const* d_in, const int* in_sizes, int n_in,
                              void* d_out, int out_size, void* d_ws, size_t ws_size,
                              hipStream_t stream) {
  const float* Q   = (const float*)d_in[0];
  const float* K   = (const float*)d_in[1];
  const float* V   = (const float*)d_in[2];
  const float* Msk = (const float*)d_in[3];
  float* Out = (float*)d_out;

  short* KVf = (short*)d_ws;                         // 16.78 MB
  short* Mg  = KVf + (size_t)8388608;                // 8.39 MB
  short* Pp  = Mg  + (size_t)4194304;                // 8.39 MB bf16 partials
  float* rsP = (float*)(Pp + (size_t)4194304);       // 0.26 MB
  int*   Fl  = (int*)(rsP + 65536);                  // 2 KB flags

  prep_all<<<dim3(KVB + MSKB), dim3(256), 0, stream>>>(K, V, Msk, KVf, Mg, Fl);
  attn_fwd<<<dim3(1024), dim3(256), 0, stream>>>(Q, KVf, Mg, Out, Pp, rsP, Fl);
}